// Round 1
// baseline (103.070 us; speedup 1.0000x reference)
//
#include <hip/hip_runtime.h>
#include <hip/hip_bf16.h>

// 2D Haar DWT, input (B=16, C=64, H=256, W=256) f32,
// output (B=16, 4*C=256, H/2=128, W/2=128) f32, channel-concat order ll,lh,hl,hh.
//
// Memory-bound: 256 MiB in + 256 MiB out. Each thread processes 2 adjacent
// 2x2 input blocks: 2x float4 loads, 4x float2 stores.

__global__ __launch_bounds__(256) void dwt2d_kernel(const float* __restrict__ x,
                                                    float* __restrict__ out) {
    // Geometry constants
    constexpr int W = 256;          // input width
    constexpr int OW = 128;         // output width
    constexpr int OH = 128;         // output height
    constexpr int C = 64;           // input channels
    // thread -> (plane, i, j4): j4 in [0,64) handles output cols 2*j4, 2*j4+1
    const unsigned tid = blockIdx.x * blockDim.x + threadIdx.x;
    const unsigned j4    = tid & 63u;          // quad-column index (4 input cols)
    const unsigned rest  = tid >> 6;
    const unsigned i     = rest & 127u;        // output row
    const unsigned plane = rest >> 7;          // b*64 + c, 0..1023

    // input base: plane*H*W + (2i)*W + 4*j4
    const size_t in_off = ((size_t)plane << 16) + ((size_t)(2u * i) << 8) + (j4 << 2);
    const float4 r0 = *reinterpret_cast<const float4*>(x + in_off);
    const float4 r1 = *reinterpret_cast<const float4*>(x + in_off + W);

    // subband values for two output columns
    const float a0 = r0.x + r0.y, d0 = r0.x - r0.y;   // row 2i, block 0
    const float a1 = r0.z + r0.w, d1 = r0.z - r0.w;   // row 2i, block 1
    const float b0 = r1.x + r1.y, e0 = r1.x - r1.y;   // row 2i+1, block 0
    const float b1 = r1.z + r1.w, e1 = r1.z - r1.w;   // row 2i+1, block 1

    const float2 ll = make_float2((a0 + b0) * 0.5f, (a1 + b1) * 0.5f);
    const float2 lh = make_float2((a0 - b0) * 0.5f, (a1 - b1) * 0.5f);
    const float2 hl = make_float2((d0 + e0) * 0.5f, (d1 + e1) * 0.5f);
    const float2 hh = make_float2((d0 - e0) * 0.5f, (d1 - e1) * 0.5f);

    // output: out[b][s*64 + c][i][2*j4 .. 2*j4+1]
    const unsigned b = plane >> 6;   // /64
    const unsigned c = plane & 63u;
    // base offset for subband s: ((b*256 + s*64 + c) * 128 + i) * 128 + 2*j4
    const size_t plane_out = ((size_t)b << 8) + c;            // b*256 + c (s=0)
    const size_t out_off0 = ((plane_out * OH + i) * OW) + (j4 << 1);
    constexpr size_t sub_stride = (size_t)C * OH * OW;        // 64*128*128 per subband

    *reinterpret_cast<float2*>(out + out_off0)                  = ll;
    *reinterpret_cast<float2*>(out + out_off0 + sub_stride)     = lh;
    *reinterpret_cast<float2*>(out + out_off0 + 2 * sub_stride) = hl;
    *reinterpret_cast<float2*>(out + out_off0 + 3 * sub_stride) = hh;
}

extern "C" void kernel_launch(void* const* d_in, const int* in_sizes, int n_in,
                              void* d_out, int out_size, void* d_ws, size_t ws_size,
                              hipStream_t stream) {
    const float* x = (const float*)d_in[0];
    float* out = (float*)d_out;
    // total threads: 16*64 planes * 128 rows * 64 quad-cols = 8,388,608
    const int total = 16 * 64 * 128 * 64;
    const int block = 256;
    const int grid = total / block;  // 32768
    dwt2d_kernel<<<grid, block, 0, stream>>>(x, out);
}

// Round 2
// 97.703 us; speedup vs baseline: 1.0549x; 1.0549x over previous
//
#include <hip/hip_runtime.h>
#include <hip/hip_bf16.h>

// 2D Haar DWT, input (B=16, C=64, H=256, W=256) f32,
// output (B=16, 4*C=256, H/2=128, W/2=128) f32, channel-concat order ll,lh,hl,hh.
//
// Memory-bound: 256 MiB in + 256 MiB out. Each thread processes 4 adjacent
// 2x2 input blocks (8 input cols x 2 rows): 4x float4 loads, 4x float4 stores
// (16 B/lane both directions).

__global__ __launch_bounds__(256) void dwt2d_kernel(const float* __restrict__ x,
                                                    float* __restrict__ out) {
    constexpr int W = 256;          // input width
    constexpr int OW = 128;         // output width
    constexpr int OH = 128;         // output height
    constexpr int C = 64;           // input channels

    // thread -> (plane, i, j8): j8 in [0,32) handles output cols 4*j8..4*j8+3
    const unsigned tid = blockIdx.x * blockDim.x + threadIdx.x;
    const unsigned j8    = tid & 31u;          // oct-column index (8 input cols)
    const unsigned rest  = tid >> 5;
    const unsigned i     = rest & 127u;        // output row
    const unsigned plane = rest >> 7;          // b*64 + c, 0..1023

    // input base: plane*H*W + (2i)*W + 8*j8
    const size_t in_off = ((size_t)plane << 16) + ((size_t)(2u * i) << 8) + (j8 << 3);
    const float4 r0a = *reinterpret_cast<const float4*>(x + in_off);
    const float4 r0b = *reinterpret_cast<const float4*>(x + in_off + 4);
    const float4 r1a = *reinterpret_cast<const float4*>(x + in_off + W);
    const float4 r1b = *reinterpret_cast<const float4*>(x + in_off + W + 4);

    // horizontal pass: sums (a) and diffs (d) per row, 4 blocks
    const float a0 = r0a.x + r0a.y, d0 = r0a.x - r0a.y;
    const float a1 = r0a.z + r0a.w, d1 = r0a.z - r0a.w;
    const float a2 = r0b.x + r0b.y, d2 = r0b.x - r0b.y;
    const float a3 = r0b.z + r0b.w, d3 = r0b.z - r0b.w;
    const float b0 = r1a.x + r1a.y, e0 = r1a.x - r1a.y;
    const float b1 = r1a.z + r1a.w, e1 = r1a.z - r1a.w;
    const float b2 = r1b.x + r1b.y, e2 = r1b.x - r1b.y;
    const float b3 = r1b.z + r1b.w, e3 = r1b.z - r1b.w;

    // vertical pass
    const float4 ll = make_float4((a0 + b0) * 0.5f, (a1 + b1) * 0.5f,
                                  (a2 + b2) * 0.5f, (a3 + b3) * 0.5f);
    const float4 lh = make_float4((a0 - b0) * 0.5f, (a1 - b1) * 0.5f,
                                  (a2 - b2) * 0.5f, (a3 - b3) * 0.5f);
    const float4 hl = make_float4((d0 + e0) * 0.5f, (d1 + e1) * 0.5f,
                                  (d2 + e2) * 0.5f, (d3 + e3) * 0.5f);
    const float4 hh = make_float4((d0 - e0) * 0.5f, (d1 - e1) * 0.5f,
                                  (d2 - e2) * 0.5f, (d3 - e3) * 0.5f);

    // output: out[b][s*64 + c][i][4*j8 .. 4*j8+3]
    const unsigned b = plane >> 6;
    const unsigned c = plane & 63u;
    const size_t plane_out = ((size_t)b << 8) + c;            // b*256 + c (s=0)
    const size_t out_off0 = ((plane_out * OH + i) * OW) + (j8 << 2);
    constexpr size_t sub_stride = (size_t)C * OH * OW;        // 64*128*128 per subband

    *reinterpret_cast<float4*>(out + out_off0)                  = ll;
    *reinterpret_cast<float4*>(out + out_off0 + sub_stride)     = lh;
    *reinterpret_cast<float4*>(out + out_off0 + 2 * sub_stride) = hl;
    *reinterpret_cast<float4*>(out + out_off0 + 3 * sub_stride) = hh;
}

extern "C" void kernel_launch(void* const* d_in, const int* in_sizes, int n_in,
                              void* d_out, int out_size, void* d_ws, size_t ws_size,
                              hipStream_t stream) {
    const float* x = (const float*)d_in[0];
    float* out = (float*)d_out;
    // total threads: 16*64 planes * 128 rows * 32 oct-cols = 4,194,304
    const int total = 16 * 64 * 128 * 32;
    const int block = 256;
    const int grid = total / block;  // 16384
    dwt2d_kernel<<<grid, block, 0, stream>>>(x, out);
}

// Round 4
// 81.027 us; speedup vs baseline: 1.2720x; 1.2058x over previous
//
#include <hip/hip_runtime.h>
#include <hip/hip_bf16.h>

// 2D Haar DWT, input (B=16, C=64, H=256, W=256) f32,
// output (B=16, 4*C=256, H/2=128, W/2=128) f32, channel-concat order ll,lh,hl,hh.
//
// Memory-bound: 256 MiB in + 256 MiB out. Each thread processes 4 adjacent
// 2x2 input blocks (8 input cols x 2 rows): 4x float4 loads, 4x 16B
// NON-TEMPORAL stores (streaming outputs have zero reuse -> evict-first).
// Native ext_vector type for the nontemporal builtin (HIP float4 is a class).

typedef float f32x4 __attribute__((ext_vector_type(4)));

__global__ __launch_bounds__(256) void dwt2d_kernel(const float* __restrict__ x,
                                                    float* __restrict__ out) {
    constexpr int W = 256;          // input width
    constexpr int OW = 128;         // output width
    constexpr int OH = 128;         // output height
    constexpr int C = 64;           // input channels

    // thread -> (plane, i, j8): j8 in [0,32) handles output cols 4*j8..4*j8+3
    const unsigned tid = blockIdx.x * blockDim.x + threadIdx.x;
    const unsigned j8    = tid & 31u;          // oct-column index (8 input cols)
    const unsigned rest  = tid >> 5;
    const unsigned i     = rest & 127u;        // output row
    const unsigned plane = rest >> 7;          // b*64 + c, 0..1023

    // input base: plane*H*W + (2i)*W + 8*j8
    const size_t in_off = ((size_t)plane << 16) + ((size_t)(2u * i) << 8) + (j8 << 3);
    const f32x4 r0a = *reinterpret_cast<const f32x4*>(x + in_off);
    const f32x4 r0b = *reinterpret_cast<const f32x4*>(x + in_off + 4);
    const f32x4 r1a = *reinterpret_cast<const f32x4*>(x + in_off + W);
    const f32x4 r1b = *reinterpret_cast<const f32x4*>(x + in_off + W + 4);

    // horizontal pass: sums (a) and diffs (d) per row, 4 blocks
    const float a0 = r0a.x + r0a.y, d0 = r0a.x - r0a.y;
    const float a1 = r0a.z + r0a.w, d1 = r0a.z - r0a.w;
    const float a2 = r0b.x + r0b.y, d2 = r0b.x - r0b.y;
    const float a3 = r0b.z + r0b.w, d3 = r0b.z - r0b.w;
    const float b0 = r1a.x + r1a.y, e0 = r1a.x - r1a.y;
    const float b1 = r1a.z + r1a.w, e1 = r1a.z - r1a.w;
    const float b2 = r1b.x + r1b.y, e2 = r1b.x - r1b.y;
    const float b3 = r1b.z + r1b.w, e3 = r1b.z - r1b.w;

    // vertical pass
    const f32x4 ll = {(a0 + b0) * 0.5f, (a1 + b1) * 0.5f,
                      (a2 + b2) * 0.5f, (a3 + b3) * 0.5f};
    const f32x4 lh = {(a0 - b0) * 0.5f, (a1 - b1) * 0.5f,
                      (a2 - b2) * 0.5f, (a3 - b3) * 0.5f};
    const f32x4 hl = {(d0 + e0) * 0.5f, (d1 + e1) * 0.5f,
                      (d2 + e2) * 0.5f, (d3 + e3) * 0.5f};
    const f32x4 hh = {(d0 - e0) * 0.5f, (d1 - e1) * 0.5f,
                      (d2 - e2) * 0.5f, (d3 - e3) * 0.5f};

    // output: out[b][s*64 + c][i][4*j8 .. 4*j8+3]
    const unsigned b = plane >> 6;
    const unsigned c = plane & 63u;
    const size_t plane_out = ((size_t)b << 8) + c;            // b*256 + c (s=0)
    const size_t out_off0 = ((plane_out * OH + i) * OW) + (j8 << 2);
    constexpr size_t sub_stride = (size_t)C * OH * OW;        // 64*128*128 per subband

    __builtin_nontemporal_store(ll, reinterpret_cast<f32x4*>(out + out_off0));
    __builtin_nontemporal_store(lh, reinterpret_cast<f32x4*>(out + out_off0 + sub_stride));
    __builtin_nontemporal_store(hl, reinterpret_cast<f32x4*>(out + out_off0 + 2 * sub_stride));
    __builtin_nontemporal_store(hh, reinterpret_cast<f32x4*>(out + out_off0 + 3 * sub_stride));
}

extern "C" void kernel_launch(void* const* d_in, const int* in_sizes, int n_in,
                              void* d_out, int out_size, void* d_ws, size_t ws_size,
                              hipStream_t stream) {
    const float* x = (const float*)d_in[0];
    float* out = (float*)d_out;
    // total threads: 16*64 planes * 128 rows * 32 oct-cols = 4,194,304
    const int total = 16 * 64 * 128 * 32;
    const int block = 256;
    const int grid = total / block;  // 16384
    dwt2d_kernel<<<grid, block, 0, stream>>>(x, out);
}